// Round 12
// baseline (307.917 us; speedup 1.0000x reference)
//
#include <hip/hip_runtime.h>
#include <hip/hip_fp16.h>

// GIN forward, round 12: back to separate kernels (per-kernel VGPR/occupancy;
// coop merge was neutral) + DEGREE-SORTED gather order. Nodes counting-sorted
// by degree (bins 0..35) so the 4 nodes sharing a wave have equal degree ->
// no max-vs-mean edge-loop divergence. Sort is folded into scan_part_k
// (per-block bin histograms) and scan_write_k (bin offsets + order scatter):
// dispatch count unchanged (14).

#define N_NODES  50000
#define N_EDGES  600000
#define N_FEAT   64
#define DIM      128
#define N_GRAPHS 1024
#define NB_SCAN  49        // ceil(50000/1024)
#define NBINS    36
#define TPB      256
#define GT128    ((N_NODES + 127) / 128)   // 391 gemm tiles

typedef _Float16 f16x8 __attribute__((ext_vector_type(8)));
typedef float    f32x4 __attribute__((ext_vector_type(4)));

#define CNTZ  (N_NODES / 4)
#define XWORK (N_NODES * N_FEAT / 4)
#define PREP_TOTAL (CNTZ + XWORK + N_FEAT * DIM + 3 * DIM * DIM)

// ---- prep: zero cnt ; x->fp16 ; W[K][128] -> Wt[128][K] fp16 ----
__global__ __launch_bounds__(TPB) void prep_k(
    const float* __restrict__ x, __half* __restrict__ xh,
    const float* __restrict__ w0, const float* __restrict__ w1,
    const float* __restrict__ w2, const float* __restrict__ w3,
    __half* __restrict__ Wt0, __half* __restrict__ Wt1,
    __half* __restrict__ Wt2, __half* __restrict__ Wt3,
    int* __restrict__ cnt) {
  int i = blockIdx.x * TPB + threadIdx.x;
  if (i < CNTZ) {
    *reinterpret_cast<int4*>(cnt + i * 4) = make_int4(0, 0, 0, 0);
    return;
  }
  i -= CNTZ;
  if (i < XWORK) {
    float4 v = *reinterpret_cast<const float4*>(x + (size_t)i * 4);
    union { __half2 h2[2]; uint2 u; } pk;
    pk.h2[0] = __floats2half2_rn(v.x, v.y);
    pk.h2[1] = __floats2half2_rn(v.z, v.w);
    *reinterpret_cast<uint2*>(xh + (size_t)i * 4) = pk.u;
    return;
  }
  int j = i - XWORK;
  if (j < N_FEAT * DIM) {
    int k = j >> 7, n = j & 127;
    Wt0[n * N_FEAT + k] = __float2half(w0[j]);
    return;
  }
  j -= N_FEAT * DIM;
  if (j >= 3 * DIM * DIM) return;
  int wsel = j / (DIM * DIM);
  int jj = j - wsel * (DIM * DIM);
  int k = jj >> 7, n = jj & 127;
  const float* W = (wsel == 0) ? w1 : (wsel == 1) ? w2 : w3;
  __half* Wt     = (wsel == 0) ? Wt1 : (wsel == 1) ? Wt2 : Wt3;
  Wt[n * DIM + k] = __float2half(W[jj]);
}

__global__ __launch_bounds__(TPB) void hist_k(
    const int* __restrict__ dst, int* __restrict__ cnt) {
  int e = blockIdx.x * TPB + threadIdx.x;
  if (e < N_EDGES) atomicAdd(&cnt[dst[e]], 1);
}

// partial sums (for row_ptr scan) + per-block degree-bin histogram
__global__ __launch_bounds__(TPB) void scan_part_k(
    const int* __restrict__ cnt, int* __restrict__ part,
    int* __restrict__ bins) {
  __shared__ int ws[4];
  __shared__ int lbin[NBINS];
  int t = threadIdx.x, b = blockIdx.x;
  if (t < NBINS) lbin[t] = 0;
  __syncthreads();
  int base = b * 1024 + t * 4;
  int s = 0;
  int v[4] = {0, 0, 0, 0};
  if (base + 3 < N_NODES) {
    int4 q = *reinterpret_cast<const int4*>(cnt + base);
    v[0] = q.x; v[1] = q.y; v[2] = q.z; v[3] = q.w;
  } else {
    for (int i = 0; i < 4; ++i) if (base + i < N_NODES) v[i] = cnt[base + i];
  }
#pragma unroll
  for (int i = 0; i < 4; ++i) {
    s += v[i];
    if (base + i < N_NODES) atomicAdd(&lbin[min(v[i], NBINS - 1)], 1);
  }
  for (int off = 32; off; off >>= 1) s += __shfl_down(s, off, 64);
  int lane = t & 63, wv = t >> 6;
  if (lane == 0) ws[wv] = s;
  __syncthreads();
  if (t == 0) part[b] = ws[0] + ws[1] + ws[2] + ws[3];
  if (t < NBINS) bins[b * NBINS + t] = lbin[t];
}

// row_ptr scan-write + fill zero + degree-sort scatter (node_order)
__global__ __launch_bounds__(TPB) void scan_write_k(
    const int* __restrict__ cnt, const int* __restrict__ part,
    const int* __restrict__ bins, int* __restrict__ row_ptr,
    int* __restrict__ fill, int* __restrict__ node_order) {
  __shared__ int wsum[4];
  __shared__ int blk_off_s;
  __shared__ int offj[NBINS];
  __shared__ int lrank[NBINS];
  int t = threadIdx.x, b = blockIdx.x;
  int lane = t & 63, wv = t >> 6;
  int base = b * 1024 + t * 4;

  if (base + 3 < N_NODES)
    *reinterpret_cast<int4*>(fill + base) = make_int4(0, 0, 0, 0);
  else
    for (int i = 0; i < 4; ++i) if (base + i < N_NODES) fill[base + i] = 0;

  // wave 0 lanes: block offset for row_ptr
  if (t < 64) {
    int v = (t < NB_SCAN) ? part[t] : 0;
    int incl = v;
    for (int off = 1; off < 64; off <<= 1) {
      int u = __shfl_up(incl, off, 64);
      if (t >= off) incl += u;
    }
    if (t == b) blk_off_s = incl - v;
  }

  // degree-bin offsets: thread j<NBINS computes column sums over blocks
  int colbelow = 0, coltot = 0;
  if (t < NBINS) {
    for (int b2 = 0; b2 < NB_SCAN; ++b2) {
      int u = bins[b2 * NBINS + t];
      if (b2 < b) colbelow += u;
      coltot += u;
    }
  }
  if (t < 64) {  // exclusive scan of coltot over bins (lanes 0..35 live)
    int v = (t < NBINS) ? coltot : 0;
    int incl = v;
    for (int off = 1; off < 64; off <<= 1) {
      int u = __shfl_up(incl, off, 64);
      if (t >= off) incl += u;
    }
    if (t < NBINS) offj[t] = (incl - v) + colbelow;
  }
  if (t < NBINS) lrank[t] = 0;

  int v[4];
#pragma unroll
  for (int i = 0; i < 4; ++i) v[i] = (base + i < N_NODES) ? cnt[base + i] : 0;
  int ls = v[0] + v[1] + v[2] + v[3];
  int incl = ls;
  for (int off = 1; off < 64; off <<= 1) {
    int u = __shfl_up(incl, off, 64);
    if (lane >= off) incl += u;
  }
  if (lane == 63) wsum[wv] = incl;
  __syncthreads();
  int woff = 0;
  for (int w = 0; w < wv; ++w) woff += wsum[w];
  int off0 = blk_off_s + woff + (incl - ls);
  int rp0 = off0, rp1 = off0 + v[0], rp2 = rp1 + v[1], rp3 = rp2 + v[2];
  if (base + 3 < N_NODES)
    *reinterpret_cast<int4*>(row_ptr + base) = make_int4(rp0, rp1, rp2, rp3);
  else {
    int rp[4] = {rp0, rp1, rp2, rp3};
    for (int i = 0; i < 4; ++i) if (base + i < N_NODES) row_ptr[base + i] = rp[i];
  }
  if (b == 0 && t == 0) row_ptr[N_NODES] = N_EDGES;

  // scatter nodes into degree-sorted order
#pragma unroll
  for (int i = 0; i < 4; ++i) {
    if (base + i < N_NODES) {
      int bin = min(v[i], NBINS - 1);
      int r = atomicAdd(&lrank[bin], 1);
      node_order[offj[bin] + r] = base + i;
    }
  }
}

__global__ __launch_bounds__(TPB) void fill_k(
    const int* __restrict__ src, const int* __restrict__ dst,
    const int* __restrict__ row_ptr, int* __restrict__ fill,
    int* __restrict__ csr_src) {
  int e = blockIdx.x * TPB + threadIdx.x;
  if (e >= N_EDGES) return;
  int d = dst[e];
  int pos = row_ptr[d] + atomicAdd(&fill[d], 1);
  csr_src[pos] = src[e];
}

// ------------- MFMA GEMM: y[M][128] = A[M][K] @ Wt[128][K]^T -------------
// 128-row tile/block; W in LDS; A direct global->VGPR; LDS repack epilogue.
template<int K, bool EPI>
__global__ __launch_bounds__(TPB) void gemm_k(
    const __half* __restrict__ A, const __half* __restrict__ Wt,
    const float* __restrict__ bias, __half* __restrict__ y) {
  constexpr int KP = K + 8;
  constexpr int OSP = 144;
  constexpr int NKC = K / 32;
  constexpr size_t WSZ = (size_t)128 * KP * sizeof(__half);
  constexpr size_t OSZ = (size_t)128 * OSP * sizeof(__half);
  __shared__ __align__(16) char smem[WSZ > OSZ ? WSZ : OSZ];
  __half (*Ws)[KP]  = reinterpret_cast<__half(*)[KP]>(smem);
  __half (*Os)[OSP] = reinterpret_cast<__half(*)[OSP]>(smem);

  int tid = threadIdx.x;
  int w = tid >> 6, lane = tid & 63;
  int quad = lane >> 4, m = lane & 15;
  int row0 = blockIdx.x * 128;

  for (int i = tid; i < 128 * (K / 8); i += TPB) {
    int r = i / (K / 8), c = (i % (K / 8)) * 8;
    *reinterpret_cast<f16x8*>(&Ws[r][c]) =
        *reinterpret_cast<const f16x8*>(Wt + (size_t)r * K + c);
  }

  f16x8 areg[2][NKC];
#pragma unroll
  for (int s = 0; s < 2; ++s) {
    int row = row0 + w * 32 + s * 16 + m;
    row = min(row, N_NODES - 1);
    const f16x8* Ar = reinterpret_cast<const f16x8*>(A + (size_t)row * K);
#pragma unroll
    for (int kc = 0; kc < NKC; ++kc)
      areg[s][kc] = Ar[kc * 4 + quad];
  }
  __syncthreads();

  f32x4 acc[2][8];
#pragma unroll
  for (int s = 0; s < 2; ++s)
#pragma unroll
    for (int t = 0; t < 8; ++t) acc[s][t] = (f32x4){0.f, 0.f, 0.f, 0.f};

#pragma unroll
  for (int kc = 0; kc < NKC; ++kc) {
#pragma unroll
    for (int t = 0; t < 8; ++t) {
      f16x8 b = *reinterpret_cast<const f16x8*>(&Ws[t * 16 + m][kc * 32 + quad * 8]);
      acc[0][t] = __builtin_amdgcn_mfma_f32_16x16x32_f16(areg[0][kc], b, acc[0][t], 0, 0, 0);
      acc[1][t] = __builtin_amdgcn_mfma_f32_16x16x32_f16(areg[1][kc], b, acc[1][t], 0, 0, 0);
    }
  }

  __syncthreads();

#pragma unroll
  for (int t = 0; t < 8; ++t) {
    float bv = EPI ? bias[t * 16 + m] : 0.f;
#pragma unroll
    for (int s = 0; s < 2; ++s)
#pragma unroll
      for (int r = 0; r < 4; ++r) {
        float v = acc[s][t][r];
        if (EPI) v = fmaxf(v + bv, 0.f);
        Os[w * 32 + s * 16 + quad * 4 + r][t * 16 + m] = __float2half(v);
      }
  }
  __syncthreads();

#pragma unroll
  for (int it = 0; it < 8; ++it) {
    int i = tid + it * TPB;
    int r = i >> 4, c = (i & 15) * 8;
    int row = row0 + r;
    if (row < N_NODES)
      *reinterpret_cast<f16x8*>(y + (size_t)row * 128 + c) =
          *reinterpret_cast<const f16x8*>(&Os[r][c]);
  }
}

// ---- gather in DEGREE-SORTED order: rank -> node_order[rank]. F/8 lanes
// per node, f16x8/lane, 4-deep unroll. Equal-degree waves -> no divergence.
template<int F, bool BR>
__global__ __launch_bounds__(TPB) void gather_k(
    const __half* __restrict__ y, const int* __restrict__ row_ptr,
    const int* __restrict__ csr_src, const int* __restrict__ order,
    const float* __restrict__ bias, __half* __restrict__ hout) {
  constexpr int CH = F / 8;
  const f16x8* yv = reinterpret_cast<const f16x8*>(y);
  int gid  = blockIdx.x * TPB + threadIdx.x;
  int rank = gid / CH;
  int l    = gid % CH;
  if (rank >= N_NODES) return;
  int node = order[rank];
  int beg = row_ptr[node], end = row_ptr[node + 1];

  f16x8 self = yv[(size_t)node * CH + l];
  float acc[8];
#pragma unroll
  for (int v = 0; v < 8; ++v) acc[v] = (float)self[v];

  int e = beg;
  for (; e + 3 < end; e += 4) {
    int s0 = csr_src[e+0], s1 = csr_src[e+1], s2 = csr_src[e+2], s3 = csr_src[e+3];
    f16x8 v0 = yv[(size_t)s0 * CH + l];
    f16x8 v1 = yv[(size_t)s1 * CH + l];
    f16x8 v2 = yv[(size_t)s2 * CH + l];
    f16x8 v3 = yv[(size_t)s3 * CH + l];
#pragma unroll
    for (int v = 0; v < 8; ++v)
      acc[v] += ((float)v0[v] + (float)v1[v]) + ((float)v2[v] + (float)v3[v]);
  }
  for (; e < end; ++e) {
    f16x8 v0 = yv[(size_t)csr_src[e] * CH + l];
#pragma unroll
    for (int v = 0; v < 8; ++v) acc[v] += (float)v0[v];
  }

  f16x8 o;
  if (BR) {
    float4 b0 = *reinterpret_cast<const float4*>(bias + l * 8);
    float4 b1 = *reinterpret_cast<const float4*>(bias + l * 8 + 4);
    float bb[8] = {b0.x, b0.y, b0.z, b0.w, b1.x, b1.y, b1.z, b1.w};
#pragma unroll
    for (int v = 0; v < 8; ++v) o[v] = (_Float16)fmaxf(acc[v] + bb[v], 0.f);
  } else {
#pragma unroll
    for (int v = 0; v < 8; ++v) o[v] = (_Float16)acc[v];
  }
  reinterpret_cast<f16x8*>(hout)[(size_t)node * CH + l] = o;
}

// ---- fused mean-pool (sorted batch) + post-MLP (fp32) ----
__global__ __launch_bounds__(128) void pool_post_k(
    const __half* __restrict__ h, const int* __restrict__ batch,
    const float* __restrict__ W, const float* __restrict__ bias,
    float* __restrict__ out) {
  __shared__ float xs[DIM];
  int g = blockIdx.x;
  int col = threadIdx.x;
  int lo = 0, hi = N_NODES;
  while (lo < hi) { int mid = (lo + hi) >> 1; if (batch[mid] < g) lo = mid + 1; else hi = mid; }
  int beg = lo;
  hi = N_NODES;
  while (lo < hi) { int mid = (lo + hi) >> 1; if (batch[mid] < g + 1) lo = mid + 1; else hi = mid; }
  int end = lo;

  float acc = 0.f;
  for (int n = beg; n < end; ++n) acc += __half2float(h[(size_t)n * DIM + col]);
  float cnt = fmaxf((float)(end - beg), 1.0f);
  xs[col] = acc / cnt;
  __syncthreads();
  float o = bias[col];
  for (int k = 0; k < DIM; ++k)
    o = fmaf(xs[k], W[(size_t)k * DIM + col], o);
  out[(size_t)g * DIM + col] = fmaxf(o, 0.f);
}

extern "C" void kernel_launch(void* const* d_in, const int* in_sizes, int n_in,
                              void* d_out, int out_size, void* d_ws, size_t ws_size,
                              hipStream_t stream) {
  const float* x    = (const float*)d_in[0];
  const int*   ei   = (const int*)d_in[1];
  const int*   batch= (const int*)d_in[2];
  const float* w0 = (const float*)d_in[3];  const float* b0 = (const float*)d_in[4];
  const float* w1 = (const float*)d_in[5];  const float* b1 = (const float*)d_in[6];
  const float* w2 = (const float*)d_in[7];  const float* b2 = (const float*)d_in[8];
  const float* w3 = (const float*)d_in[9];  const float* b3 = (const float*)d_in[10];
  const float* wp = (const float*)d_in[11]; const float* bp = (const float*)d_in[12];
  float* out = (float*)d_out;

  const int* src = ei;
  const int* dst = ei + N_EDGES;

  __half* xh = (__half*)d_ws;
  __half* y  = xh + (size_t)N_NODES * N_FEAT;
  __half* h  = y  + (size_t)N_NODES * DIM;
  __half* Wt0 = h + (size_t)N_NODES * DIM;
  __half* Wt1 = Wt0 + N_FEAT * DIM;
  __half* Wt2 = Wt1 + DIM * DIM;
  __half* Wt3 = Wt2 + DIM * DIM;
  int* cnt     = (int*)(Wt3 + DIM * DIM);
  int* fill    = cnt + N_NODES;
  int* part    = fill + N_NODES;
  int* row_ptr = part + 64;
  int* csr_src = row_ptr + (N_NODES + 1);
  int* node_order = csr_src + N_EDGES;
  int* bins       = node_order + N_NODES;      // NB_SCAN*NBINS
  __half* s = y;   // 64-wide staging for layer 0

  // ---- prep (zeros cnt) + CSR build + degree sort ----
  prep_k<<<(PREP_TOTAL + TPB - 1) / TPB, TPB, 0, stream>>>(
      x, xh, w0, w1, w2, w3, Wt0, Wt1, Wt2, Wt3, cnt);
  hist_k<<<(N_EDGES + TPB - 1) / TPB, TPB, 0, stream>>>(dst, cnt);
  scan_part_k <<<NB_SCAN, TPB, 0, stream>>>(cnt, part, bins);
  scan_write_k<<<NB_SCAN, TPB, 0, stream>>>(cnt, part, bins, row_ptr, fill,
                                            node_order);
  fill_k<<<(N_EDGES + TPB - 1) / TPB, TPB, 0, stream>>>(src, dst, row_ptr,
                                                        fill, csr_src);

  // ---- layer 0: s = x + agg(x) (64-wide), h = relu(s@W0 + b0) ----
  gather_k<N_FEAT, false><<<(N_NODES * 8 + TPB - 1) / TPB, TPB, 0, stream>>>(
      xh, row_ptr, csr_src, node_order, nullptr, s);
  gemm_k<N_FEAT, true><<<GT128, TPB, 0, stream>>>(s, Wt0, b0, h);

  // ---- layers 1..3 ----
  const __half* Wl[3] = {Wt1, Wt2, Wt3};
  const float*  Bl[3] = {b1, b2, b3};
  for (int l = 0; l < 3; ++l) {
    gemm_k<DIM, false><<<GT128, TPB, 0, stream>>>(h, Wl[l], nullptr, y);
    gather_k<DIM, true><<<(N_NODES * 16 + TPB - 1) / TPB, TPB, 0, stream>>>(
        y, row_ptr, csr_src, node_order, Bl[l], h);
  }

  // ---- pool + post-MLP ----
  pool_post_k<<<N_GRAPHS, 128, 0, stream>>>(h, batch, wp, bp, out);
}

// Round 13
// 300.504 us; speedup vs baseline: 1.0247x; 1.0247x over previous
//
#include <hip/hip_runtime.h>
#include <hip/hip_fp16.h>

// GIN forward, round 13: SOURCE-CHUNKED CSR. Edges binned by key
// (dst, src>>13): within each row edges are sorted by source chunk
// (7 chunks x 8192 nodes = 2MB of y per chunk at 128-wide), so co-resident
// gather waves walk y chunk-by-chunk and the hot region fits per-XCD L2
// (4MB). Gather kernel itself unchanged (R7 shape). Degree-sort dropped
// (R12: measured neutral).

#define N_NODES  50000
#define N_EDGES  600000
#define N_FEAT   64
#define DIM      128
#define N_GRAPHS 1024
#define NC       7           // src chunks: src>>13, 0..6
#define CSH      13
#define TOT2     (N_NODES * NC)          // 350000 bins
#define SCH      2048                    // scan elems per block
#define NBLK     ((TOT2 + SCH - 1) / SCH)  // 171
#define TPB      256
#define GT128    ((N_NODES + 127) / 128)   // 391 gemm tiles

typedef _Float16 f16x8 __attribute__((ext_vector_type(8)));
typedef float    f32x4 __attribute__((ext_vector_type(4)));

#define CNTZ2 (TOT2 / 4)                 // 87500 int4 items
#define XWORK (N_NODES * N_FEAT / 4)
#define PREP_TOTAL (CNTZ2 + XWORK + N_FEAT * DIM + 3 * DIM * DIM)

// ---- prep: zero cnt2 ; x->fp16 ; W[K][128] -> Wt[128][K] fp16 ----
__global__ __launch_bounds__(TPB) void prep_k(
    const float* __restrict__ x, __half* __restrict__ xh,
    const float* __restrict__ w0, const float* __restrict__ w1,
    const float* __restrict__ w2, const float* __restrict__ w3,
    __half* __restrict__ Wt0, __half* __restrict__ Wt1,
    __half* __restrict__ Wt2, __half* __restrict__ Wt3,
    int* __restrict__ cnt2) {
  int i = blockIdx.x * TPB + threadIdx.x;
  if (i < CNTZ2) {
    *reinterpret_cast<int4*>(cnt2 + i * 4) = make_int4(0, 0, 0, 0);
    return;
  }
  i -= CNTZ2;
  if (i < XWORK) {
    float4 v = *reinterpret_cast<const float4*>(x + (size_t)i * 4);
    union { __half2 h2[2]; uint2 u; } pk;
    pk.h2[0] = __floats2half2_rn(v.x, v.y);
    pk.h2[1] = __floats2half2_rn(v.z, v.w);
    *reinterpret_cast<uint2*>(xh + (size_t)i * 4) = pk.u;
    return;
  }
  int j = i - XWORK;
  if (j < N_FEAT * DIM) {
    int k = j >> 7, n = j & 127;
    Wt0[n * N_FEAT + k] = __float2half(w0[j]);
    return;
  }
  j -= N_FEAT * DIM;
  if (j >= 3 * DIM * DIM) return;
  int wsel = j / (DIM * DIM);
  int jj = j - wsel * (DIM * DIM);
  int k = jj >> 7, n = jj & 127;
  const float* W = (wsel == 0) ? w1 : (wsel == 1) ? w2 : w3;
  __half* Wt     = (wsel == 0) ? Wt1 : (wsel == 1) ? Wt2 : Wt3;
  Wt[n * DIM + k] = __float2half(W[jj]);
}

// ---- histogram over (dst, src-chunk) keys ----
__global__ __launch_bounds__(TPB) void hist_k(
    const int* __restrict__ src, const int* __restrict__ dst,
    int* __restrict__ cnt2) {
  int e = blockIdx.x * TPB + threadIdx.x;
  if (e >= N_EDGES) return;
  int key = dst[e] * NC + (src[e] >> CSH);
  atomicAdd(&cnt2[key], 1);
}

// ---- scan phase 1: per-block (2048 elems) partial sums ----
__global__ __launch_bounds__(TPB) void scan_part_k(
    const int* __restrict__ cnt2, int* __restrict__ part) {
  __shared__ int ws[4];
  int t = threadIdx.x, b = blockIdx.x;
  int base = b * SCH + t * 8;
  int s = 0;
  if (base < TOT2) {    // TOT2 % 8 == 0: all 8 in-bounds together
    int4 a = *reinterpret_cast<const int4*>(cnt2 + base);
    int4 c = *reinterpret_cast<const int4*>(cnt2 + base + 4);
    s = a.x + a.y + a.z + a.w + c.x + c.y + c.z + c.w;
  }
  for (int off = 32; off; off >>= 1) s += __shfl_down(s, off, 64);
  int lane = t & 63, wv = t >> 6;
  if (lane == 0) ws[wv] = s;
  __syncthreads();
  if (t == 0) part[b] = ws[0] + ws[1] + ws[2] + ws[3];
}

// ---- scan phase 2: LDS scan of NBLK partials + intra-block scan-write
//      + fill2 zeroing ----
__global__ __launch_bounds__(TPB) void scan_write_k(
    const int* __restrict__ cnt2, const int* __restrict__ part,
    int* __restrict__ row_ptr2, int* __restrict__ fill2) {
  __shared__ int pscan[TPB];
  __shared__ int wsum[4];
  int t = threadIdx.x, b = blockIdx.x;
  int lane = t & 63, wv = t >> 6;
  int base = b * SCH + t * 8;

  // zero fill2 (same coverage as row_ptr2 writes)
  if (base < TOT2) {
    *reinterpret_cast<int4*>(fill2 + base) = make_int4(0, 0, 0, 0);
    *reinterpret_cast<int4*>(fill2 + base + 4) = make_int4(0, 0, 0, 0);
  }

  // block offset: Hillis-Steele over NBLK partials in LDS
  pscan[t] = (t < NBLK) ? part[t] : 0;
  __syncthreads();
  for (int off = 1; off < TPB; off <<= 1) {
    int v = (t >= off) ? pscan[t - off] : 0;
    __syncthreads();
    pscan[t] += v;
    __syncthreads();
  }
  int blk_off = (b > 0) ? pscan[b - 1] : 0;

  int v[8] = {0,0,0,0,0,0,0,0};
  if (base < TOT2) {
    int4 a = *reinterpret_cast<const int4*>(cnt2 + base);
    int4 c = *reinterpret_cast<const int4*>(cnt2 + base + 4);
    v[0]=a.x; v[1]=a.y; v[2]=a.z; v[3]=a.w;
    v[4]=c.x; v[5]=c.y; v[6]=c.z; v[7]=c.w;
  }
  int ls = 0;
#pragma unroll
  for (int i = 0; i < 8; ++i) ls += v[i];
  int incl = ls;
  for (int off = 1; off < 64; off <<= 1) {
    int u = __shfl_up(incl, off, 64);
    if (lane >= off) incl += u;
  }
  if (lane == 63) wsum[wv] = incl;
  __syncthreads();
  int woff = 0;
  for (int w = 0; w < wv; ++w) woff += wsum[w];
  int run = blk_off + woff + (incl - ls);
  if (base < TOT2) {
    int rp[8];
#pragma unroll
    for (int i = 0; i < 8; ++i) { rp[i] = run; run += v[i]; }
    *reinterpret_cast<int4*>(row_ptr2 + base) = make_int4(rp[0], rp[1], rp[2], rp[3]);
    *reinterpret_cast<int4*>(row_ptr2 + base + 4) = make_int4(rp[4], rp[5], rp[6], rp[7]);
  }
  if (b == 0 && t == 0) row_ptr2[TOT2] = N_EDGES;
}

// ---- fill: place edge at its (dst, chunk) slot ----
__global__ __launch_bounds__(TPB) void fill_k(
    const int* __restrict__ src, const int* __restrict__ dst,
    const int* __restrict__ row_ptr2, int* __restrict__ fill2,
    int* __restrict__ csr_src) {
  int e = blockIdx.x * TPB + threadIdx.x;
  if (e >= N_EDGES) return;
  int s = src[e];
  int key = dst[e] * NC + (s >> CSH);
  int pos = row_ptr2[key] + atomicAdd(&fill2[key], 1);
  csr_src[pos] = s;
}

// ------------- MFMA GEMM: y[M][128] = A[M][K] @ Wt[128][K]^T -------------
template<int K, bool EPI>
__global__ __launch_bounds__(TPB) void gemm_k(
    const __half* __restrict__ A, const __half* __restrict__ Wt,
    const float* __restrict__ bias, __half* __restrict__ y) {
  constexpr int KP = K + 8;
  constexpr int OSP = 144;
  constexpr int NKC = K / 32;
  constexpr size_t WSZ = (size_t)128 * KP * sizeof(__half);
  constexpr size_t OSZ = (size_t)128 * OSP * sizeof(__half);
  __shared__ __align__(16) char smem[WSZ > OSZ ? WSZ : OSZ];
  __half (*Ws)[KP]  = reinterpret_cast<__half(*)[KP]>(smem);
  __half (*Os)[OSP] = reinterpret_cast<__half(*)[OSP]>(smem);

  int tid = threadIdx.x;
  int w = tid >> 6, lane = tid & 63;
  int quad = lane >> 4, m = lane & 15;
  int row0 = blockIdx.x * 128;

  for (int i = tid; i < 128 * (K / 8); i += TPB) {
    int r = i / (K / 8), c = (i % (K / 8)) * 8;
    *reinterpret_cast<f16x8*>(&Ws[r][c]) =
        *reinterpret_cast<const f16x8*>(Wt + (size_t)r * K + c);
  }

  f16x8 areg[2][NKC];
#pragma unroll
  for (int s = 0; s < 2; ++s) {
    int row = row0 + w * 32 + s * 16 + m;
    row = min(row, N_NODES - 1);
    const f16x8* Ar = reinterpret_cast<const f16x8*>(A + (size_t)row * K);
#pragma unroll
    for (int kc = 0; kc < NKC; ++kc)
      areg[s][kc] = Ar[kc * 4 + quad];
  }
  __syncthreads();

  f32x4 acc[2][8];
#pragma unroll
  for (int s = 0; s < 2; ++s)
#pragma unroll
    for (int t = 0; t < 8; ++t) acc[s][t] = (f32x4){0.f, 0.f, 0.f, 0.f};

#pragma unroll
  for (int kc = 0; kc < NKC; ++kc) {
#pragma unroll
    for (int t = 0; t < 8; ++t) {
      f16x8 b = *reinterpret_cast<const f16x8*>(&Ws[t * 16 + m][kc * 32 + quad * 8]);
      acc[0][t] = __builtin_amdgcn_mfma_f32_16x16x32_f16(areg[0][kc], b, acc[0][t], 0, 0, 0);
      acc[1][t] = __builtin_amdgcn_mfma_f32_16x16x32_f16(areg[1][kc], b, acc[1][t], 0, 0, 0);
    }
  }

  __syncthreads();

#pragma unroll
  for (int t = 0; t < 8; ++t) {
    float bv = EPI ? bias[t * 16 + m] : 0.f;
#pragma unroll
    for (int s = 0; s < 2; ++s)
#pragma unroll
      for (int r = 0; r < 4; ++r) {
        float v = acc[s][t][r];
        if (EPI) v = fmaxf(v + bv, 0.f);
        Os[w * 32 + s * 16 + quad * 4 + r][t * 16 + m] = __float2half(v);
      }
  }
  __syncthreads();

#pragma unroll
  for (int it = 0; it < 8; ++it) {
    int i = tid + it * TPB;
    int r = i >> 4, c = (i & 15) * 8;
    int row = row0 + r;
    if (row < N_NODES)
      *reinterpret_cast<f16x8*>(y + (size_t)row * 128 + c) =
          *reinterpret_cast<const f16x8*>(&Os[r][c]);
  }
}

// ---- gather (R7 shape): F/8 lanes/node, f16x8/lane, 4-deep unroll.
// Edge list is chunk-ordered -> co-resident waves share an L2-resident
// y-window. row_ptr2 has stride NC per node.
template<int F, bool BR>
__global__ __launch_bounds__(TPB) void gather_k(
    const __half* __restrict__ y, const int* __restrict__ row_ptr2,
    const int* __restrict__ csr_src, const float* __restrict__ bias,
    __half* __restrict__ hout) {
  constexpr int CH = F / 8;
  const f16x8* yv = reinterpret_cast<const f16x8*>(y);
  int gid  = blockIdx.x * TPB + threadIdx.x;
  int node = gid / CH;
  int l    = gid % CH;
  if (node >= N_NODES) return;
  int beg = row_ptr2[node * NC];
  int end = row_ptr2[node * NC + NC];

  f16x8 self = yv[(size_t)node * CH + l];
  float acc[8];
#pragma unroll
  for (int v = 0; v < 8; ++v) acc[v] = (float)self[v];

  int e = beg;
  for (; e + 3 < end; e += 4) {
    int s0 = csr_src[e+0], s1 = csr_src[e+1], s2 = csr_src[e+2], s3 = csr_src[e+3];
    f16x8 v0 = yv[(size_t)s0 * CH + l];
    f16x8 v1 = yv[(size_t)s1 * CH + l];
    f16x8 v2 = yv[(size_t)s2 * CH + l];
    f16x8 v3 = yv[(size_t)s3 * CH + l];
#pragma unroll
    for (int v = 0; v < 8; ++v)
      acc[v] += ((float)v0[v] + (float)v1[v]) + ((float)v2[v] + (float)v3[v]);
  }
  for (; e < end; ++e) {
    f16x8 v0 = yv[(size_t)csr_src[e] * CH + l];
#pragma unroll
    for (int v = 0; v < 8; ++v) acc[v] += (float)v0[v];
  }

  f16x8 o;
  if (BR) {
    float4 b0 = *reinterpret_cast<const float4*>(bias + l * 8);
    float4 b1 = *reinterpret_cast<const float4*>(bias + l * 8 + 4);
    float bb[8] = {b0.x, b0.y, b0.z, b0.w, b1.x, b1.y, b1.z, b1.w};
#pragma unroll
    for (int v = 0; v < 8; ++v) o[v] = (_Float16)fmaxf(acc[v] + bb[v], 0.f);
  } else {
#pragma unroll
    for (int v = 0; v < 8; ++v) o[v] = (_Float16)acc[v];
  }
  reinterpret_cast<f16x8*>(hout)[(size_t)node * CH + l] = o;
}

// ---- fused mean-pool (sorted batch) + post-MLP (fp32) ----
__global__ __launch_bounds__(128) void pool_post_k(
    const __half* __restrict__ h, const int* __restrict__ batch,
    const float* __restrict__ W, const float* __restrict__ bias,
    float* __restrict__ out) {
  __shared__ float xs[DIM];
  int g = blockIdx.x;
  int col = threadIdx.x;
  int lo = 0, hi = N_NODES;
  while (lo < hi) { int mid = (lo + hi) >> 1; if (batch[mid] < g) lo = mid + 1; else hi = mid; }
  int beg = lo;
  hi = N_NODES;
  while (lo < hi) { int mid = (lo + hi) >> 1; if (batch[mid] < g + 1) lo = mid + 1; else hi = mid; }
  int end = lo;

  float acc = 0.f;
  for (int n = beg; n < end; ++n) acc += __half2float(h[(size_t)n * DIM + col]);
  float cnt = fmaxf((float)(end - beg), 1.0f);
  xs[col] = acc / cnt;
  __syncthreads();
  float o = bias[col];
  for (int k = 0; k < DIM; ++k)
    o = fmaf(xs[k], W[(size_t)k * DIM + col], o);
  out[(size_t)g * DIM + col] = fmaxf(o, 0.f);
}

extern "C" void kernel_launch(void* const* d_in, const int* in_sizes, int n_in,
                              void* d_out, int out_size, void* d_ws, size_t ws_size,
                              hipStream_t stream) {
  const float* x    = (const float*)d_in[0];
  const int*   ei   = (const int*)d_in[1];
  const int*   batch= (const int*)d_in[2];
  const float* w0 = (const float*)d_in[3];  const float* b0 = (const float*)d_in[4];
  const float* w1 = (const float*)d_in[5];  const float* b1 = (const float*)d_in[6];
  const float* w2 = (const float*)d_in[7];  const float* b2 = (const float*)d_in[8];
  const float* w3 = (const float*)d_in[9];  const float* b3 = (const float*)d_in[10];
  const float* wp = (const float*)d_in[11]; const float* bp = (const float*)d_in[12];
  float* out = (float*)d_out;

  const int* src = ei;
  const int* dst = ei + N_EDGES;

  __half* xh = (__half*)d_ws;
  __half* y  = xh + (size_t)N_NODES * N_FEAT;
  __half* h  = y  + (size_t)N_NODES * DIM;
  __half* Wt0 = h + (size_t)N_NODES * DIM;
  __half* Wt1 = Wt0 + N_FEAT * DIM;
  __half* Wt2 = Wt1 + DIM * DIM;
  __half* Wt3 = Wt2 + DIM * DIM;
  int* cnt2     = (int*)(Wt3 + DIM * DIM);
  int* fill2    = cnt2 + TOT2;
  int* part     = fill2 + TOT2;
  int* row_ptr2 = part + 256;
  int* csr_src  = row_ptr2 + (TOT2 + 1);
  __half* s = y;   // 64-wide staging for layer 0

  // ---- prep (zeros cnt2) + chunked-CSR build ----
  prep_k<<<(PREP_TOTAL + TPB - 1) / TPB, TPB, 0, stream>>>(
      x, xh, w0, w1, w2, w3, Wt0, Wt1, Wt2, Wt3, cnt2);
  hist_k<<<(N_EDGES + TPB - 1) / TPB, TPB, 0, stream>>>(src, dst, cnt2);
  scan_part_k <<<NBLK, TPB, 0, stream>>>(cnt2, part);
  scan_write_k<<<NBLK, TPB, 0, stream>>>(cnt2, part, row_ptr2, fill2);
  fill_k<<<(N_EDGES + TPB - 1) / TPB, TPB, 0, stream>>>(src, dst, row_ptr2,
                                                        fill2, csr_src);

  // ---- layer 0: s = x + agg(x) (64-wide), h = relu(s@W0 + b0) ----
  gather_k<N_FEAT, false><<<(N_NODES * 8 + TPB - 1) / TPB, TPB, 0, stream>>>(
      xh, row_ptr2, csr_src, nullptr, s);
  gemm_k<N_FEAT, true><<<GT128, TPB, 0, stream>>>(s, Wt0, b0, h);

  // ---- layers 1..3 ----
  const __half* Wl[3] = {Wt1, Wt2, Wt3};
  const float*  Bl[3] = {b1, b2, b3};
  for (int l = 0; l < 3; ++l) {
    gemm_k<DIM, false><<<GT128, TPB, 0, stream>>>(h, Wl[l], nullptr, y);
    gather_k<DIM, true><<<(N_NODES * 16 + TPB - 1) / TPB, TPB, 0, stream>>>(
        y, row_ptr2, csr_src, Bl[l], h);
  }

  // ---- pool + post-MLP ----
  pool_post_k<<<N_GRAPHS, 128, 0, stream>>>(h, batch, wp, bp, out);
}